// Round 14
// baseline (1151.745 us; speedup 1.0000x reference)
//
#include <hip/hip_runtime.h>
#include <stdint.h>
#include <string.h>

#define PXI 4800
#define NPAD 5084   // 62*82 padded pixels
#define BNI 24

typedef short bf16x8 __attribute__((ext_vector_type(8)));
typedef float f32x4 __attribute__((ext_vector_type(4)));

__device__ __forceinline__ uint16_t f2b(float f) {
  uint32_t u = __float_as_uint(f);
  u += 0x7fffu + ((u >> 16) & 1u);
  return (uint16_t)(u >> 16);
}
__device__ __forceinline__ float b2f(uint16_t b) {
  return __uint_as_float(((uint32_t)b) << 16);
}
__device__ __forceinline__ float sigm(float x) {
  return 1.0f / (1.0f + __expf(-x));
}

struct SrcDesc {
  const void* p;
  int nstride;    // elements per image
  int coff;       // starting channel of this 32-ch kstep within source
  int pixstride;  // NHWC channel count (bf16 path)
  int creal;      // valid channel bound (f32 path)
  int is_f32;     // 1 = NCHW f32 source, 0 = NHWC bf16 source
  int padded;     // 1 = 62x82 zero-border padded NHWC (fast staging path)
};

struct ConvParams {
  SrcDesc srcs[14];
  int KS, cog_total, ncb, mode;
  int opad0, opad1;       // outputs padded?
  const uint16_t* wpk;
  const float* bias0;
  const float* bias1;
  uint16_t* out0; int ostride0, ochoff0;
  uint16_t* out1; int ostride1, ochoff1;
  const uint16_t* zbuf;   // mode 2 (unpadded 128)
  const uint16_t* hbf;    // mode 1: h as bf16 padded NHWC stride 448
  const float* netf32;    // mode 2: h (f32 NCHW, unpadded)
  float* houtf32;         // mode 2: net_out region of d_out (unpadded)
};

// Implicit-GEMM conv v4.3: v4.1 (verified 927us / zr 245us / VGPR 84) plus
// ONE register-neutral change: padded-source fast staging. Intermediates are
// stored 62x82 with zero borders, so 3x3-conv staging is a single
// unconditional load (no bounds cmp / cndmask / zero-fill). MFMA loop,
// A-prefetch pipeline, acc layout byte-identical to v4.1.
// Register equilibrium: 84 arch + 80 acc = 164 unified -> 3 waves/SIMD.
template<int DSPAN, int CW>
__global__ __launch_bounds__(256, 2) void conv_mfma(ConvParams P) {
  constexpr int PAD = (DSPAN - 1) / 2;
  constexpr int NR = 2;
  constexpr int NRS = NR + DSPAN - 1;
  constexpr int UP = 80 + 2 * PAD;
  constexpr int UPITCH = 82 * 64;
  constexpr int NT = DSPAN * DSPAN;
  constexpr int CB = 4 * CW;
  __shared__ __align__(16) uint8_t smem[NRS * UPITCH];
  const int tid = threadIdx.x;
  const int wave = tid >> 6, lane = tid & 63;
  const int bx = blockIdx.x;
  const int total = gridDim.x;
  const int id = (bx & 7) * (total >> 3) + (bx >> 3);  // XCD-contiguous
  const int cbk = id % P.ncb;
  const int rg = id / P.ncb;           // cog-blocks of same rows adjacent
  const int n = rg / 30, y0 = (rg - n * 30) * NR;
  const int cog0 = cbk * CB + wave * CW;

  f32x4 acc[CW][NR][5];
#pragma unroll
  for (int c = 0; c < CW; ++c)
#pragma unroll
    for (int r = 0; r < NR; ++r)
#pragma unroll
      for (int t = 0; t < 5; ++t)
        acc[c][r][t] = f32x4{0.f, 0.f, 0.f, 0.f};

  const int pxl = lane & 15;
  const int hi16 = (lane >> 4) * 16;
  const int tapstride = P.cog_total * P.KS * 512;   // elements per tap
  const uint16_t* wl = P.wpk + lane * 8;

  for (int ks = 0; ks < P.KS; ++ks) {
    __syncthreads();   // prev-ks MFMA reads done
    // ---- A tap-0 prefetch: global-only, issued before B-staging so its L2
    // latency overlaps the whole staging phase.
    const uint16_t* wk0 = wl + ((size_t)cog0 * P.KS + ks) * 512;
    bf16x8 acur[CW];
#pragma unroll
    for (int c = 0; c < CW; ++c)
      acur[c] = *(const bf16x8*)(wk0 + (size_t)c * (P.KS * 512));
    // ---- stage B: NRS source rows x 32 ch
    const SrcDesc d = P.srcs[ks];
    if (d.padded) {
      // fast path: padded 62x82 source, logical (ysrc,xs) -> padded (ysrc+1,
      // xs+1) = (y0+rs, u) for PAD=1. Single unconditional load.
      const uint16_t* bp = (const uint16_t*)d.p + (size_t)n * d.nstride + d.coff;
      for (int c = tid; c < NRS * UP * 4; c += 256) {
        int rs = c / (UP * 4);
        int rem = c - rs * (UP * 4);
        int u = rem >> 2, kq = rem & 3;
        uint4 v = *(const uint4*)(bp + (size_t)((y0 + rs) * 82 + u) * d.pixstride + kq * 8);
        *(uint4*)(smem + rs * UPITCH + ((u * 64 + kq * 16) ^ ((u & 7) << 4))) = v;
      }
    } else if (!d.is_f32) {
      const uint16_t* bp = (const uint16_t*)d.p + (size_t)n * d.nstride + d.coff;
      for (int c = tid; c < NRS * UP * 4; c += 256) {
        int rs = c / (UP * 4);
        int rem = c - rs * (UP * 4);
        int u = rem >> 2, kq = rem & 3;
        int ysrc = y0 + rs - PAD;
        int xs = u - PAD;
        uint4 v; v.x = 0; v.y = 0; v.z = 0; v.w = 0;
        if ((unsigned)ysrc < 60u && (unsigned)xs < 80u)
          v = *(const uint4*)(bp + (size_t)(ysrc * 80 + xs) * d.pixstride + kq * 8);
        *(uint4*)(smem + rs * UPITCH + ((u * 64 + kq * 16) ^ ((u & 7) << 4))) = v;
      }
    } else {
      // f32 NCHW path (ce1 only: 1x1, pad 0)
      const int ci = tid >> 3, xg = tid & 7;
      const bool cok = (d.coff + ci) < d.creal;
      const float* fp = (const float*)d.p + (size_t)n * d.nstride +
                        (size_t)(d.coff + ci) * PXI;
#pragma unroll
      for (int rs = 0; rs < NRS; ++rs) {
#pragma unroll
        for (int j = 0; j < 10; ++j) {
          int x = xg + j * 8;
          float v = cok ? fp[(y0 + rs) * 80 + x] : 0.f;
          *(uint16_t*)(smem + rs * UPITCH + ((x * 64 + ci * 2) ^ ((x & 7) << 4))) = f2b(v);
        }
      }
    }
    __syncthreads();
    // ---- tap loop: unroll-1; tap+1 A-frags prefetch during tap's MFMAs
#pragma unroll 1
    for (int tap = 0; tap < NT; ++tap) {
      bf16x8 anx[CW];
      if (tap + 1 < NT) {
        const uint16_t* wn = wk0 + (size_t)(tap + 1) * tapstride;
#pragma unroll
        for (int c = 0; c < CW; ++c)
          anx[c] = *(const bf16x8*)(wn + (size_t)c * (P.KS * 512));
      }
      const int dy = (DSPAN == 3) ? ((tap * 11) >> 5) : 0;
      const int dx = tap - dy * 3;
      const int u0 = pxl + dx;
      const uint8_t* brow = smem + dy * UPITCH + ((u0 * 64 + hi16) ^ ((u0 & 7) << 4));
#pragma unroll
      for (int r = 0; r < NR; ++r) {
#pragma unroll
        for (int t = 0; t < 5; ++t) {
          bf16x8 b = *(const bf16x8*)(brow + r * UPITCH + t * 1024);
#pragma unroll
          for (int c = 0; c < CW; ++c)
            acc[c][r][t] = __builtin_amdgcn_mfma_f32_16x16x32_bf16(acur[c], b, acc[c][r][t], 0, 0, 0);
        }
      }
      if (tap + 1 < NT) {
#pragma unroll
        for (int c = 0; c < CW; ++c)
          acur[c] = anx[c];
      }
    }
  }

  // ---- epilogue
  const int rq = lane >> 4;
  for (int c = 0; c < CW; ++c) {
    const int co0 = (cog0 + c) * 16 + rq * 4;
    for (int r = 0; r < NR; ++r) {
      for (int t = 0; t < 5; ++t) {
        const int Y = y0 + r, X = t * 16 + pxl;
        const int px = Y * 80 + X;
        const size_t gpu = (size_t)n * PXI + px;                    // unpadded
        const size_t gpp = (size_t)n * NPAD + (Y + 1) * 82 + (X + 1); // padded
        float v[4];
#pragma unroll
        for (int rr = 0; rr < 4; ++rr) {
          int co = co0 + rr;
          float bia = (P.bias1 && co >= 128) ? P.bias1[co - 128] : P.bias0[co];
          v[rr] = acc[c][r][t][rr] + bia;
        }
        if (P.mode == 0) {           // relu -> bf16 NHWC (split at co>=128 if out1)
          uint16_t* op; int cb2;
          if (P.out1 && co0 >= 128) {
            op = P.out1 + (P.opad1 ? gpp : gpu) * (size_t)P.ostride1 + P.ochoff1;
            cb2 = co0 - 128;
          } else {
            op = P.out0 + (P.opad0 ? gpp : gpu) * (size_t)P.ostride0 + P.ochoff0;
            cb2 = co0;
          }
          uint64_t w = 0;
#pragma unroll
          for (int rr = 0; rr < 4; ++rr)
            w |= (uint64_t)f2b(fmaxf(v[rr], 0.f)) << (16 * rr);
          *(uint64_t*)(op + cb2) = w;
        } else if (P.mode == 1) {    // z (sigmoid, unpadded) / r*h (padded)
          if (co0 < 128) {
            uint64_t w = 0;
#pragma unroll
            for (int rr = 0; rr < 4; ++rr)
              w |= (uint64_t)f2b(sigm(v[rr])) << (16 * rr);
            *(uint64_t*)(P.out0 + gpu * 128 + co0) = w;
          } else {
            uint64_t hw = *(const uint64_t*)(P.hbf + gpp * 448 + (co0 - 128));
            uint64_t w = 0;
#pragma unroll
            for (int rr = 0; rr < 4; ++rr) {
              float rgt = sigm(v[rr]);
              float h = b2f((uint16_t)(hw >> (16 * rr)));
              w |= (uint64_t)f2b(rgt * h) << (16 * rr);
            }
            *(uint64_t*)(P.out1 + gpp * 128 + (co0 - 128)) = w;
          }
        } else {                     // mode 2: q=tanh, GRU update, dual write
          uint64_t zw = *(const uint64_t*)(P.zbuf + gpu * 128 + co0);
          uint64_t w = 0;
#pragma unroll
          for (int rr = 0; rr < 4; ++rr) {
            float qv = tanhf(v[rr]);
            float z = b2f((uint16_t)(zw >> (16 * rr)));
            size_t hidx = ((size_t)n * 128 + co0 + rr) * PXI + px;
            float h = P.netf32[hidx];
            float hn = (1.f - z) * h + z * qv;
            P.houtf32[hidx] = hn;
            w |= (uint64_t)f2b(hn) << (16 * rr);
          }
          *(uint64_t*)(P.out0 + (P.opad0 ? gpp : gpu) * 128 + co0) = w;
        }
      }
    }
  }
}

// zero the 62x82 borders of a padded NHWC buffer (CS channels, uint4 chunks)
__global__ __launch_bounds__(256) void zero_borders(uint16_t* buf, int CS) {
  int vecs = CS >> 3;
  int idx = blockIdx.x * 256 + threadIdx.x;
  int tot = BNI * 284 * vecs;
  if (idx >= tot) return;
  int v = idx % vecs; int rest = idx / vecs;
  int b = rest % 284; int n = rest / 284;
  int r, c;
  if (b < 164) { r = (b < 82) ? 0 : 61; c = (b < 82) ? b : b - 82; }
  else { int b2 = b - 164; r = 1 + (b2 % 60); c = (b2 < 60) ? 0 : 81; }
  uint4 z; z.x = 0; z.y = 0; z.z = 0; z.w = 0;
  *(uint4*)(buf + ((size_t)n * NPAD + r * 82 + c) * CS + v * 8) = z;
}

// f32 NCHW -> bf16 padded NHWC (62x82 interior)
__global__ __launch_bounds__(256) void nchw2nhwc(const float* src, uint16_t* dst,
                                                 int C, int pixstride, int choff) {
  const int n = blockIdx.y;
  const int px = blockIdx.x * 256 + threadIdx.x;
  if (px >= PXI) return;
  const float* sp = src + (size_t)n * C * PXI + px;
  uint16_t* dp = dst + ((size_t)n * NPAD + (px / 80 + 1) * 82 + (px % 80 + 1)) * pixstride + choff;
  for (int c = 0; c < C; c += 8) {
    uint32_t pk[4];
#pragma unroll
    for (int j = 0; j < 4; ++j) {
      uint32_t lo = f2b(sp[(size_t)(c + 2 * j) * PXI]);
      uint32_t hi = f2b(sp[(size_t)(c + 2 * j + 1) * PXI]);
      pk[j] = lo | (hi << 16);
    }
    uint4 v; v.x = pk[0]; v.y = pk[1]; v.z = pk[2]; v.w = pk[3];
    *(uint4*)(dp + c) = v;
  }
}

// im2col for fe1: flow (24x3x60x80 f32) -> F2col[n][px][160] bf16 (unpadded),
// k = ci*49 + ky*7 + kx (147 real, pad->160), pad=3 halo, OOB=0.
__global__ __launch_bounds__(256) void im2col_fe1(const float* flow, uint16_t* F2col) {
  __shared__ float tile[3 * 7 * 88];
  __shared__ uint32_t lut[160];
  const int y = blockIdx.x, n = blockIdx.y;
  const int tid = threadIdx.x;
  if (tid < 160) {
    int k = tid;
    if (k < 147) {
      int ci = k / 49, rem = k - ci * 49;
      int ky = rem / 7, kx = rem - ky * 7;
      lut[k] = (uint32_t)ci | ((uint32_t)ky << 8) | ((uint32_t)kx << 16);
    } else lut[k] = 0xFFFFFFFFu;
  }
  for (int c = tid; c < 3 * 7 * 86; c += 256) {
    int ci = c / 602, rem = c - ci * 602;
    int ky = rem / 86, xi = rem - ky * 86;
    int ysrc = y + ky - 3, x = xi - 3;
    float v = 0.f;
    if ((unsigned)ysrc < 60u && (unsigned)x < 80u)
      v = flow[((size_t)(n * 3 + ci) * 60 + ysrc) * 80 + x];
    tile[(ci * 7 + ky) * 88 + xi] = v;
  }
  __syncthreads();
  uint16_t* op = F2col + ((size_t)n * PXI + y * 80) * 160;
  for (int c = tid; c < 80 * 20; c += 256) {
    int px = c / 20, q = c - px * 20;
    int k0 = q * 8;
    uint32_t pk[4];
#pragma unroll
    for (int j = 0; j < 4; ++j) {
      uint16_t w0 = 0, w1 = 0;
      uint32_t l0 = lut[k0 + 2 * j], l1 = lut[k0 + 2 * j + 1];
      if (l0 != 0xFFFFFFFFu)
        w0 = f2b(tile[((l0 & 0xFF) * 7 + ((l0 >> 8) & 0xFF)) * 88 + px + (l0 >> 16)]);
      if (l1 != 0xFFFFFFFFu)
        w1 = f2b(tile[((l1 & 0xFF) * 7 + ((l1 >> 8) & 0xFF)) * 88 + px + (l1 >> 16)]);
      pk[j] = (uint32_t)w0 | ((uint32_t)w1 << 16);
    }
    uint4 v; v.x = pk[0]; v.y = pk[1]; v.z = pk[2]; v.w = pk[3];
    *(uint4*)(op + (size_t)px * 160 + k0) = v;
  }
}

// Pack f32 OIHW weights -> bf16 MFMA-fragment-order:
// wpk[((tap*cogTotal + cog)*KS + ks)*512 + lane*8 + e],
// lane = (co&15) | (((ci>>3)&3)<<4), e = ci&7, ks = ci>>5. Cin zero-padded to CPAD.
__global__ __launch_bounds__(256) void pack_w(const float* w, uint16_t* wpk,
    int Cout, int Cin, int taps, int CPAD, int cobase, int cogTotal) {
  int idx = blockIdx.x * 256 + threadIdx.x;
  int total = Cout * CPAD * taps;
  if (idx >= total) return;
  int ci = idx % CPAD;
  int rest = idx / CPAD;
  int co = rest % Cout;
  int tap = rest / Cout;
  float v = (ci < Cin) ? w[((size_t)co * Cin + ci) * taps + tap] : 0.f;
  int cog = (cobase + co) >> 4;
  int ks = ci >> 5;
  int lane = ((cobase + co) & 15) | (((ci >> 3) & 3) << 4);
  int KS = CPAD >> 5;
  size_t off = ((size_t)(tap * cogTotal + cog) * KS + ks) * 512 + lane * 8 + (ci & 7);
  wpk[off] = f2b(v);
}

// heads conv2: 3x3, 128->3 each (delta raw, weight sigmoid), vectorized loads.
// D1/W1 are UNPADDED 128-stride buffers. wl layout: [src][tap][j][ci].
__global__ __launch_bounds__(256) void dw2_kernel(const uint16_t* D1, const uint16_t* W1,
    const float* wd, const float* wwt, const float* bd, const float* bw,
    float* out_delta, float* out_weight) {
  __shared__ float wl[2 * 9 * 3 * 128];
  const int tid = threadIdx.x;
  for (int c = tid; c < 6912; c += 256) {
    int s = c / 3456, rem = c - s * 3456;
    int j = rem / 1152, rem2 = rem - j * 1152;
    int ci = rem2 / 9, tap = rem2 - ci * 9;
    const float* src = s ? wwt : wd;
    wl[((s * 9 + tap) * 3 + j) * 128 + ci] = src[rem];
  }
  __syncthreads();
  int gid = blockIdx.x * 256 + tid;
  if (gid >= BNI * PXI) return;
  int n = gid / PXI, px = gid - n * PXI;
  int y = px / 80, x = px - y * 80;
  float accd[3] = {bd[0], bd[1], bd[2]};
  float accw[3] = {bw[0], bw[1], bw[2]};
  for (int tap = 0; tap < 9; ++tap) {
    int dy = tap / 3, dxm = tap - dy * 3;
    int ys = y + dy - 1, xs = x + dxm - 1;
    if ((unsigned)ys >= 60u || (unsigned)xs >= 80u) continue;
    const uint16_t* dp = D1 + ((size_t)n * PXI + ys * 80 + xs) * 128;
    const uint16_t* wp = W1 + ((size_t)n * PXI + ys * 80 + xs) * 128;
    const float* wtd = &wl[(0 * 9 + tap) * 3 * 128];
    const float* wtw = &wl[(9 + tap) * 3 * 128];
    for (int cq = 0; cq < 16; ++cq) {
      uint4 dv4 = *(const uint4*)(dp + cq * 8);
      uint4 wv4 = *(const uint4*)(wp + cq * 8);
      float dv[8], wv[8];
      const uint32_t* du = (const uint32_t*)&dv4;
      const uint32_t* wu = (const uint32_t*)&wv4;
#pragma unroll
      for (int e = 0; e < 4; ++e) {
        dv[2 * e] = b2f((uint16_t)du[e]); dv[2 * e + 1] = b2f((uint16_t)(du[e] >> 16));
        wv[2 * e] = b2f((uint16_t)wu[e]); wv[2 * e + 1] = b2f((uint16_t)(wu[e] >> 16));
      }
#pragma unroll
      for (int j = 0; j < 3; ++j) {
        f32x4 wa = *(const f32x4*)(wtd + j * 128 + cq * 8);
        f32x4 wb = *(const f32x4*)(wtd + j * 128 + cq * 8 + 4);
        f32x4 va = *(const f32x4*)(wtw + j * 128 + cq * 8);
        f32x4 vb = *(const f32x4*)(wtw + j * 128 + cq * 8 + 4);
#pragma unroll
        for (int e = 0; e < 4; ++e) {
          accd[j] += dv[e] * wa[e] + dv[e + 4] * wb[e];
          accw[j] += wv[e] * va[e] + wv[e + 4] * vb[e];
        }
      }
    }
  }
  size_t ob = ((size_t)n * PXI + px) * 3;
#pragma unroll
  for (int j = 0; j < 3; ++j) {
    out_delta[ob + j] = accd[j];
    out_weight[ob + j] = sigm(accw[j]);
  }
}

extern "C" void kernel_launch(void* const* d_in, const int* in_sizes, int n_in,
                              void* d_out, int out_size, void* d_ws, size_t ws_size,
                              hipStream_t stream) {
  (void)in_sizes; (void)n_in; (void)out_size; (void)ws_size;
  const float* net  = (const float*)d_in[0];
  const float* inp  = (const float*)d_in[1];
  const float* corr = (const float*)d_in[2];
  const float* flow = (const float*)d_in[3];
  const float* w_ce1 = (const float*)d_in[4];   const float* b_ce1 = (const float*)d_in[5];
  const float* w_ce2 = (const float*)d_in[6];   const float* b_ce2 = (const float*)d_in[7];
  const float* w_fe1 = (const float*)d_in[8];   const float* b_fe1 = (const float*)d_in[9];
  const float* w_fe2 = (const float*)d_in[10];  const float* b_fe2 = (const float*)d_in[11];
  const float* w_z  = (const float*)d_in[12];   const float* b_z  = (const float*)d_in[13];
  const float* w_r  = (const float*)d_in[14];   const float* b_r  = (const float*)d_in[15];
  const float* w_q  = (const float*)d_in[16];   const float* b_q  = (const float*)d_in[17];
  const float* w_d1 = (const float*)d_in[18];   const float* b_d1 = (const float*)d_in[19];
  const float* w_d2 = (const float*)d_in[20];   const float* b_d2 = (const float*)d_in[21];
  const float* w_w1 = (const float*)d_in[22];   const float* b_w1 = (const float*)d_in[23];
  const float* w_w2 = (const float*)d_in[24];   const float* b_w2 = (const float*)d_in[25];

  uint8_t* ws = (uint8_t*)d_ws;
  size_t off = 0;
  auto alloc = [&](size_t b) { size_t o = off; off += (b + 255) & ~(size_t)255; return o; };
  uint16_t* wpk_ce1 = (uint16_t*)(ws + alloc(57344));
  uint16_t* wpk_ce2 = (uint16_t*)(ws + alloc(294912));
  uint16_t* wpk_fe1 = (uint16_t*)(ws + alloc(40960));
  uint16_t* wpk_fe2 = (uint16_t*)(ws + alloc(147456));
  uint16_t* wpk_zr  = (uint16_t*)(ws + alloc(2064384));
  uint16_t* wpk_q   = (uint16_t*)(ws + alloc(1032192));
  uint16_t* wpk_dw  = (uint16_t*)(ws + alloc(589824));
  uint16_t* X448 = (uint16_t*)(ws + alloc((size_t)BNI * NPAD * 448 * 2)); // padded [h|inp|c|fl]
  uint16_t* C1   = (uint16_t*)(ws + alloc((size_t)BNI * NPAD * 128 * 2)); // padded: ce1 out -> HN
  uint16_t* F1   = (uint16_t*)(ws + alloc((size_t)BNI * NPAD * 128 * 2)); // padded: fe1 out
  uint16_t* Zb   = (uint16_t*)(ws + alloc((size_t)BNI * PXI * 128 * 2));  // unpadded: z -> D1
  uint16_t* RHb  = (uint16_t*)(ws + alloc((size_t)BNI * NPAD * 128 * 2)); // padded: r*h
  // F2col (36.9MB, unpadded 160-ch) aliases Zb + head of RHb: both dead
  // until zr writes them, and fe1 conv consumes F2col before zr.
  uint16_t* F2col = Zb;
  // W1 head output aliases X448 (dead after q conv). Unpadded 128-stride.
  uint16_t* W1buf = X448;

  auto packs = [&](const float* w, uint16_t* dst, int Cout, int Cin, int taps,
                   int CPAD, int cobase, int cogT) {
    int total = Cout * CPAD * taps;
    pack_w<<<(total + 255) / 256, 256, 0, stream>>>(w, dst, Cout, Cin, taps, CPAD, cobase, cogT);
  };
  packs(w_ce1, wpk_ce1, 128, 197, 1, 224, 0, 8);
  packs(w_ce2, wpk_ce2, 128, 128, 9, 128, 0, 8);
  packs(w_fe1, wpk_fe1, 128, 147, 1, 160, 0, 8);
  packs(w_fe2, wpk_fe2, 64, 128, 9, 128, 0, 4);
  packs(w_z,  wpk_zr, 128, 448, 9, 448, 0, 16);
  packs(w_r,  wpk_zr, 128, 448, 9, 448, 128, 16);
  packs(w_q,  wpk_q,  128, 448, 9, 448, 0, 8);
  packs(w_d1, wpk_dw, 128, 128, 9, 128, 0, 16);
  packs(w_w1, wpk_dw, 128, 128, 9, 128, 128, 16);

  // border zeroing (RHb deferred: its storage tail is aliased by F2col)
  zero_borders<<<(BNI * 284 * 56 + 255) / 256, 256, 0, stream>>>(X448, 448);
  zero_borders<<<(BNI * 284 * 16 + 255) / 256, 256, 0, stream>>>(C1, 128);
  zero_borders<<<(BNI * 284 * 16 + 255) / 256, 256, 0, stream>>>(F1, 128);

  nchw2nhwc<<<dim3(19, BNI), 256, 0, stream>>>(net, X448, 128, 448, 0);
  nchw2nhwc<<<dim3(19, BNI), 256, 0, stream>>>(inp, X448, 128, 448, 128);
  im2col_fe1<<<dim3(60, BNI), 256, 0, stream>>>(flow, F2col);

  const int GR = BNI * 30;  // 720 rowgroups (2 rows each), divisible by 8
  ConvParams p;
  // ---- fe1 as 1x1 MFMA conv: F2col(160, unpadded) -> F1 (padded), relu
  memset(&p, 0, sizeof(p));
  for (int ks = 0; ks < 5; ++ks) p.srcs[ks] = SrcDesc{F2col, PXI * 160, ks * 32, 160, 0, 0, 0};
  p.KS = 5; p.cog_total = 8; p.ncb = 1; p.mode = 0; p.opad0 = 1;
  p.wpk = wpk_fe1; p.bias0 = b_fe1;
  p.out0 = F1; p.ostride0 = 128; p.ochoff0 = 0;
  conv_mfma<1, 2><<<GR, 256, 0, stream>>>(p);
  // F2col consumed -> RHb storage is now free: zero its borders
  zero_borders<<<(BNI * 284 * 16 + 255) / 256, 256, 0, stream>>>(RHb, 128);
  // ---- ce1: 1x1, corr(197 f32) -> C1 (padded), relu
  memset(&p, 0, sizeof(p));
  for (int ks = 0; ks < 7; ++ks) p.srcs[ks] = SrcDesc{corr, 197 * PXI, ks * 32, 0, 197, 1, 0};
  p.KS = 7; p.cog_total = 8; p.ncb = 1; p.mode = 0; p.opad0 = 1;
  p.wpk = wpk_ce1; p.bias0 = b_ce1;
  p.out0 = C1; p.ostride0 = 128; p.ochoff0 = 0;
  conv_mfma<1, 2><<<GR, 256, 0, stream>>>(p);
  // ---- ce2: 3x3, C1 (padded) -> X448[256:384) (padded), relu
  memset(&p, 0, sizeof(p));
  for (int ks = 0; ks < 4; ++ks) p.srcs[ks] = SrcDesc{C1, NPAD * 128, ks * 32, 128, 0, 0, 1};
  p.KS = 4; p.cog_total = 8; p.ncb = 1; p.mode = 0; p.opad0 = 1;
  p.wpk = wpk_ce2; p.bias0 = b_ce2;
  p.out0 = X448; p.ostride0 = 448; p.ochoff0 = 256;
  conv_mfma<3, 2><<<GR, 256, 0, stream>>>(p);
  // ---- fe2: 3x3, F1 (padded) -> X448[384:448) (padded), relu (Cout=64)
  memset(&p, 0, sizeof(p));
  for (int ks = 0; ks < 4; ++ks) p.srcs[ks] = SrcDesc{F1, NPAD * 128, ks * 32, 128, 0, 0, 1};
  p.KS = 4; p.cog_total = 4; p.ncb = 1; p.mode = 0; p.opad0 = 1;
  p.wpk = wpk_fe2; p.bias0 = b_fe2;
  p.out0 = X448; p.ostride0 = 448; p.ochoff0 = 384;
  conv_mfma<3, 1><<<GR, 256, 0, stream>>>(p);
  // ---- z & r fused: 3x3, X448 (padded) -> Z(Zb unpadded), RH(RHb padded)
  memset(&p, 0, sizeof(p));
  for (int ks = 0; ks < 14; ++ks) p.srcs[ks] = SrcDesc{X448, NPAD * 448, ks * 32, 448, 0, 0, 1};
  p.KS = 14; p.cog_total = 16; p.ncb = 2; p.mode = 1; p.opad1 = 1;
  p.wpk = wpk_zr; p.bias0 = b_z; p.bias1 = b_r;
  p.out0 = Zb; p.out1 = RHb; p.hbf = X448;
  conv_mfma<3, 2><<<GR * 2, 256, 0, stream>>>(p);
  // ---- q: 3x3, [RH (padded) | X448[128:448) (padded)] -> tanh, GRU update
  //      -> d_out(net, unpadded NCHW) + HN(C1, padded)
  memset(&p, 0, sizeof(p));
  for (int ks = 0; ks < 4; ++ks)  p.srcs[ks] = SrcDesc{RHb, NPAD * 128, ks * 32, 128, 0, 0, 1};
  for (int ks = 4; ks < 14; ++ks) p.srcs[ks] = SrcDesc{X448, NPAD * 448, 128 + (ks - 4) * 32, 448, 0, 0, 1};
  p.KS = 14; p.cog_total = 8; p.ncb = 1; p.mode = 2; p.opad0 = 1;
  p.wpk = wpk_q; p.bias0 = b_q;
  p.out0 = C1; p.zbuf = Zb; p.netf32 = net; p.houtf32 = (float*)d_out;
  conv_mfma<3, 2><<<GR, 256, 0, stream>>>(p);
  // ---- d1 & w1 fused: 3x3, HN(C1 padded) -> D1(Zb unpadded), W1(W1buf unpadded)
  memset(&p, 0, sizeof(p));
  for (int ks = 0; ks < 4; ++ks) p.srcs[ks] = SrcDesc{C1, NPAD * 128, ks * 32, 128, 0, 0, 1};
  p.KS = 4; p.cog_total = 16; p.ncb = 2; p.mode = 0;
  p.wpk = wpk_dw; p.bias0 = b_d1; p.bias1 = b_w1;
  p.out0 = Zb; p.ostride0 = 128; p.ochoff0 = 0;
  p.out1 = W1buf; p.ostride1 = 128; p.ochoff1 = 0;
  conv_mfma<3, 2><<<GR * 2, 256, 0, stream>>>(p);
  // ---- heads final convs
  float* dout = (float*)d_out;
  dw2_kernel<<<450, 256, 0, stream>>>(Zb, W1buf, w_d2, w_w2, b_d2, b_w2,
                                      dout + 14745600, dout + 15091200);
}

// Round 15
// 928.234 us; speedup vs baseline: 1.2408x; 1.2408x over previous
//
#include <hip/hip_runtime.h>
#include <stdint.h>
#include <string.h>

#define PXI 4800
#define BNI 24

typedef short bf16x8 __attribute__((ext_vector_type(8)));
typedef float f32x4 __attribute__((ext_vector_type(4)));

__device__ __forceinline__ uint16_t f2b(float f) {
  uint32_t u = __float_as_uint(f);
  u += 0x7fffu + ((u >> 16) & 1u);
  return (uint16_t)(u >> 16);
}
__device__ __forceinline__ float b2f(uint16_t b) {
  return __uint_as_float(((uint32_t)b) << 16);
}
__device__ __forceinline__ float sigm(float x) {
  return 1.0f / (1.0f + __expf(-x));
}

struct SrcDesc {
  const void* p;
  int nstride;    // elements per image
  int coff;       // starting channel of this 32-ch kstep within source
  int pixstride;  // NHWC channel count (bf16 path)
  int creal;      // valid channel bound (f32 path)
  int is_f32;     // 1 = NCHW f32 source, 0 = NHWC bf16 source
};

struct ConvParams {
  SrcDesc srcs[14];
  int KS, cog_total, ncb, mode;
  const uint16_t* wpk;
  const float* bias0;
  const float* bias1;
  uint16_t* out0; int ostride0, ochoff0;
  uint16_t* out1; int ostride1, ochoff1;
  const uint16_t* zbuf;   // mode 2
  const uint16_t* hbf;    // mode 1: h as bf16 NHWC stride 448
  const float* netf32;    // mode 2: h (f32 NCHW)
  float* houtf32;         // mode 2: net_out region of d_out
};

// Implicit-GEMM conv v4.1 (FINAL verified optimum: 927us total / zr 245us /
// VGPR 84 / MfmaUtil 44%). v4 + A-loads software-pipelined by one tap.
// Register equilibrium: 84 arch + 80 acc = 164 unified -> 3 waves/SIMD.
// Every tested neighbor regresses: +16 regs (B-dbuf, r12) and +12 regs
// (padded staging, r14) both drop to 2 waves/SIMD (-11%/-24%); CWW=8
// variants (r6-r8) spill or collapse occupancy. Do not perturb.
template<int DSPAN, int CW>
__global__ __launch_bounds__(256, 2) void conv_mfma(ConvParams P) {
  constexpr int PAD = (DSPAN - 1) / 2;
  constexpr int NR = 2;
  constexpr int NRS = NR + DSPAN - 1;
  constexpr int UP = 80 + 2 * PAD;
  constexpr int UPITCH = 82 * 64;
  constexpr int NT = DSPAN * DSPAN;
  constexpr int CB = 4 * CW;
  __shared__ __align__(16) uint8_t smem[NRS * UPITCH];
  const int tid = threadIdx.x;
  const int wave = tid >> 6, lane = tid & 63;
  const int bx = blockIdx.x;
  const int total = gridDim.x;
  const int id = (bx & 7) * (total >> 3) + (bx >> 3);  // XCD-contiguous
  const int cbk = id % P.ncb;
  const int rg = id / P.ncb;           // cog-blocks of same rows adjacent
  const int n = rg / 30, y0 = (rg - n * 30) * NR;
  const int cog0 = cbk * CB + wave * CW;

  f32x4 acc[CW][NR][5];
#pragma unroll
  for (int c = 0; c < CW; ++c)
#pragma unroll
    for (int r = 0; r < NR; ++r)
#pragma unroll
      for (int t = 0; t < 5; ++t)
        acc[c][r][t] = f32x4{0.f, 0.f, 0.f, 0.f};

  const int pxl = lane & 15;
  const int hi16 = (lane >> 4) * 16;
  const int tapstride = P.cog_total * P.KS * 512;   // elements per tap
  const uint16_t* wl = P.wpk + lane * 8;

  for (int ks = 0; ks < P.KS; ++ks) {
    __syncthreads();   // prev-ks MFMA reads done
    // ---- A tap-0 prefetch: global-only, issued before B-staging so its L2
    // latency overlaps the whole staging phase.
    const uint16_t* wk0 = wl + ((size_t)cog0 * P.KS + ks) * 512;
    bf16x8 acur[CW];
#pragma unroll
    for (int c = 0; c < CW; ++c)
      acur[c] = *(const bf16x8*)(wk0 + (size_t)c * (P.KS * 512));
    // ---- stage B: NRS source rows x 32 ch, halo'd, swizzled
    const SrcDesc d = P.srcs[ks];
    if (!d.is_f32) {
      const uint16_t* bp = (const uint16_t*)d.p + (size_t)n * d.nstride + d.coff;
      for (int c = tid; c < NRS * UP * 4; c += 256) {
        int rs = c / (UP * 4);
        int rem = c - rs * (UP * 4);
        int u = rem >> 2, kq = rem & 3;
        int ysrc = y0 + rs - PAD;
        int xs = u - PAD;
        uint4 v; v.x = 0; v.y = 0; v.z = 0; v.w = 0;
        if ((unsigned)ysrc < 60u && (unsigned)xs < 80u)
          v = *(const uint4*)(bp + (size_t)(ysrc * 80 + xs) * d.pixstride + kq * 8);
        *(uint4*)(smem + rs * UPITCH + ((u * 64 + kq * 16) ^ ((u & 7) << 4))) = v;
      }
    } else {
      // f32 NCHW path (ce1 only: 1x1, pad 0)
      const int ci = tid >> 3, xg = tid & 7;
      const bool cok = (d.coff + ci) < d.creal;
      const float* fp = (const float*)d.p + (size_t)n * d.nstride +
                        (size_t)(d.coff + ci) * PXI;
#pragma unroll
      for (int rs = 0; rs < NRS; ++rs) {
#pragma unroll
        for (int j = 0; j < 10; ++j) {
          int x = xg + j * 8;
          float v = cok ? fp[(y0 + rs) * 80 + x] : 0.f;
          *(uint16_t*)(smem + rs * UPITCH + ((x * 64 + ci * 2) ^ ((x & 7) << 4))) = f2b(v);
        }
      }
    }
    __syncthreads();
    // ---- tap loop: unroll-1; tap+1 A-frags prefetch during tap's MFMAs
#pragma unroll 1
    for (int tap = 0; tap < NT; ++tap) {
      bf16x8 anx[CW];
      if (tap + 1 < NT) {
        const uint16_t* wn = wk0 + (size_t)(tap + 1) * tapstride;
#pragma unroll
        for (int c = 0; c < CW; ++c)
          anx[c] = *(const bf16x8*)(wn + (size_t)c * (P.KS * 512));
      }
      const int dy = (DSPAN == 3) ? ((tap * 11) >> 5) : 0;
      const int dx = tap - dy * 3;
      const int u0 = pxl + dx;
      const uint8_t* brow = smem + dy * UPITCH + ((u0 * 64 + hi16) ^ ((u0 & 7) << 4));
#pragma unroll
      for (int r = 0; r < NR; ++r) {
#pragma unroll
        for (int t = 0; t < 5; ++t) {
          bf16x8 b = *(const bf16x8*)(brow + r * UPITCH + t * 1024);
#pragma unroll
          for (int c = 0; c < CW; ++c)
            acc[c][r][t] = __builtin_amdgcn_mfma_f32_16x16x32_bf16(acur[c], b, acc[c][r][t], 0, 0, 0);
        }
      }
      if (tap + 1 < NT) {
#pragma unroll
        for (int c = 0; c < CW; ++c)
          acur[c] = anx[c];
      }
    }
  }

  // ---- epilogue
  const int rq = lane >> 4;
  for (int c = 0; c < CW; ++c) {
    const int co0 = (cog0 + c) * 16 + rq * 4;
    for (int r = 0; r < NR; ++r) {
      for (int t = 0; t < 5; ++t) {
        const int px = (y0 + r) * 80 + t * 16 + pxl;
        const size_t gpix = (size_t)n * PXI + px;
        float v[4];
#pragma unroll
        for (int rr = 0; rr < 4; ++rr) {
          int co = co0 + rr;
          float bia = (P.bias1 && co >= 128) ? P.bias1[co - 128] : P.bias0[co];
          v[rr] = acc[c][r][t][rr] + bia;
        }
        if (P.mode == 0) {           // relu -> bf16 NHWC (split at co>=128 if out1)
          uint16_t* op; int cb2;
          if (P.out1 && co0 >= 128) { op = P.out1 + gpix * (size_t)P.ostride1 + P.ochoff1; cb2 = co0 - 128; }
          else                      { op = P.out0 + gpix * (size_t)P.ostride0 + P.ochoff0; cb2 = co0; }
          uint64_t w = 0;
#pragma unroll
          for (int rr = 0; rr < 4; ++rr)
            w |= (uint64_t)f2b(fmaxf(v[rr], 0.f)) << (16 * rr);
          *(uint64_t*)(op + cb2) = w;
        } else if (P.mode == 1) {    // z (sigmoid) / r (sigmoid * h_bf16)
          if (co0 < 128) {
            uint64_t w = 0;
#pragma unroll
            for (int rr = 0; rr < 4; ++rr)
              w |= (uint64_t)f2b(sigm(v[rr])) << (16 * rr);
            *(uint64_t*)(P.out0 + gpix * 128 + co0) = w;
          } else {
            uint64_t hw = *(const uint64_t*)(P.hbf + gpix * 448 + (co0 - 128));
            uint64_t w = 0;
#pragma unroll
            for (int rr = 0; rr < 4; ++rr) {
              float rgt = sigm(v[rr]);
              float h = b2f((uint16_t)(hw >> (16 * rr)));
              w |= (uint64_t)f2b(rgt * h) << (16 * rr);
            }
            *(uint64_t*)(P.out1 + gpix * 128 + (co0 - 128)) = w;
          }
        } else {                     // mode 2: q=tanh, GRU update, dual write
          uint64_t zw = *(const uint64_t*)(P.zbuf + gpix * 128 + co0);
          uint64_t w = 0;
#pragma unroll
          for (int rr = 0; rr < 4; ++rr) {
            float qv = tanhf(v[rr]);
            float z = b2f((uint16_t)(zw >> (16 * rr)));
            size_t hidx = ((size_t)n * 128 + co0 + rr) * PXI + px;
            float h = P.netf32[hidx];
            float hn = (1.f - z) * h + z * qv;
            P.houtf32[hidx] = hn;
            w |= (uint64_t)f2b(hn) << (16 * rr);
          }
          *(uint64_t*)(P.out0 + gpix * 128 + co0) = w;
        }
      }
    }
  }
}

// f32 NCHW -> bf16 NHWC transpose
__global__ __launch_bounds__(256) void nchw2nhwc(const float* src, uint16_t* dst,
                                                 int C, int pixstride, int choff) {
  const int n = blockIdx.y;
  const int px = blockIdx.x * 256 + threadIdx.x;
  if (px >= PXI) return;
  const float* sp = src + (size_t)n * C * PXI + px;
  uint16_t* dp = dst + ((size_t)n * PXI + px) * pixstride + choff;
  for (int c = 0; c < C; c += 8) {
    uint32_t pk[4];
#pragma unroll
    for (int j = 0; j < 4; ++j) {
      uint32_t lo = f2b(sp[(size_t)(c + 2 * j) * PXI]);
      uint32_t hi = f2b(sp[(size_t)(c + 2 * j + 1) * PXI]);
      pk[j] = lo | (hi << 16);
    }
    uint4 v; v.x = pk[0]; v.y = pk[1]; v.z = pk[2]; v.w = pk[3];
    *(uint4*)(dp + c) = v;
  }
}

// im2col for fe1: flow (24x3x60x80 f32) -> F2col[n][px][160] bf16,
// k = ci*49 + ky*7 + kx (147 real, pad->160), pad=3 halo, OOB=0.
__global__ __launch_bounds__(256) void im2col_fe1(const float* flow, uint16_t* F2col) {
  __shared__ float tile[3 * 7 * 88];
  __shared__ uint32_t lut[160];
  const int y = blockIdx.x, n = blockIdx.y;
  const int tid = threadIdx.x;
  if (tid < 160) {
    int k = tid;
    if (k < 147) {
      int ci = k / 49, rem = k - ci * 49;
      int ky = rem / 7, kx = rem - ky * 7;
      lut[k] = (uint32_t)ci | ((uint32_t)ky << 8) | ((uint32_t)kx << 16);
    } else lut[k] = 0xFFFFFFFFu;
  }
  for (int c = tid; c < 3 * 7 * 86; c += 256) {
    int ci = c / 602, rem = c - ci * 602;
    int ky = rem / 86, xi = rem - ky * 86;
    int ysrc = y + ky - 3, x = xi - 3;
    float v = 0.f;
    if ((unsigned)ysrc < 60u && (unsigned)x < 80u)
      v = flow[((size_t)(n * 3 + ci) * 60 + ysrc) * 80 + x];
    tile[(ci * 7 + ky) * 88 + xi] = v;
  }
  __syncthreads();
  uint16_t* op = F2col + ((size_t)n * PXI + y * 80) * 160;
  for (int c = tid; c < 80 * 20; c += 256) {
    int px = c / 20, q = c - px * 20;
    int k0 = q * 8;
    uint32_t pk[4];
#pragma unroll
    for (int j = 0; j < 4; ++j) {
      uint16_t w0 = 0, w1 = 0;
      uint32_t l0 = lut[k0 + 2 * j], l1 = lut[k0 + 2 * j + 1];
      if (l0 != 0xFFFFFFFFu)
        w0 = f2b(tile[((l0 & 0xFF) * 7 + ((l0 >> 8) & 0xFF)) * 88 + px + (l0 >> 16)]);
      if (l1 != 0xFFFFFFFFu)
        w1 = f2b(tile[((l1 & 0xFF) * 7 + ((l1 >> 8) & 0xFF)) * 88 + px + (l1 >> 16)]);
      pk[j] = (uint32_t)w0 | ((uint32_t)w1 << 16);
    }
    uint4 v; v.x = pk[0]; v.y = pk[1]; v.z = pk[2]; v.w = pk[3];
    *(uint4*)(op + (size_t)px * 160 + k0) = v;
  }
}

// Pack f32 OIHW weights -> bf16 MFMA-fragment-order:
// wpk[((tap*cogTotal + cog)*KS + ks)*512 + lane*8 + e],
// lane = (co&15) | (((ci>>3)&3)<<4), e = ci&7, ks = ci>>5. Cin zero-padded to CPAD.
__global__ __launch_bounds__(256) void pack_w(const float* w, uint16_t* wpk,
    int Cout, int Cin, int taps, int CPAD, int cobase, int cogTotal) {
  int idx = blockIdx.x * 256 + threadIdx.x;
  int total = Cout * CPAD * taps;
  if (idx >= total) return;
  int ci = idx % CPAD;
  int rest = idx / CPAD;
  int co = rest % Cout;
  int tap = rest / Cout;
  float v = (ci < Cin) ? w[((size_t)co * Cin + ci) * taps + tap] : 0.f;
  int cog = (cobase + co) >> 4;
  int ks = ci >> 5;
  int lane = ((cobase + co) & 15) | (((ci >> 3) & 3) << 4);
  int KS = CPAD >> 5;
  size_t off = ((size_t)(tap * cogTotal + cog) * KS + ks) * 512 + lane * 8 + (ci & 7);
  wpk[off] = f2b(v);
}

// heads conv2: 3x3, 128->3 each (delta raw, weight sigmoid), vectorized loads.
// wl layout: [src][tap][j][ci] for float4 LDS reads.
__global__ __launch_bounds__(256) void dw2_kernel(const uint16_t* D1, const uint16_t* W1,
    const float* wd, const float* wwt, const float* bd, const float* bw,
    float* out_delta, float* out_weight) {
  __shared__ float wl[2 * 9 * 3 * 128];
  const int tid = threadIdx.x;
  for (int c = tid; c < 6912; c += 256) {
    int s = c / 3456, rem = c - s * 3456;
    // rem indexes [j][ci][tap] of the source
    int j = rem / 1152, rem2 = rem - j * 1152;
    int ci = rem2 / 9, tap = rem2 - ci * 9;
    const float* src = s ? wwt : wd;
    wl[((s * 9 + tap) * 3 + j) * 128 + ci] = src[rem];
  }
  __syncthreads();
  int gid = blockIdx.x * 256 + tid;
  if (gid >= BNI * PXI) return;
  int n = gid / PXI, px = gid - n * PXI;
  int y = px / 80, x = px - y * 80;
  float accd[3] = {bd[0], bd[1], bd[2]};
  float accw[3] = {bw[0], bw[1], bw[2]};
  for (int tap = 0; tap < 9; ++tap) {
    int dy = tap / 3, dxm = tap - dy * 3;
    int ys = y + dy - 1, xs = x + dxm - 1;
    if ((unsigned)ys >= 60u || (unsigned)xs >= 80u) continue;
    const uint16_t* dp = D1 + ((size_t)n * PXI + ys * 80 + xs) * 128;
    const uint16_t* wp = W1 + ((size_t)n * PXI + ys * 80 + xs) * 128;
    const float* wtd = &wl[(0 * 9 + tap) * 3 * 128];
    const float* wtw = &wl[(9 + tap) * 3 * 128];
    for (int cq = 0; cq < 16; ++cq) {
      uint4 dv4 = *(const uint4*)(dp + cq * 8);
      uint4 wv4 = *(const uint4*)(wp + cq * 8);
      float dv[8], wv[8];
      const uint32_t* du = (const uint32_t*)&dv4;
      const uint32_t* wu = (const uint32_t*)&wv4;
#pragma unroll
      for (int e = 0; e < 4; ++e) {
        dv[2 * e] = b2f((uint16_t)du[e]); dv[2 * e + 1] = b2f((uint16_t)(du[e] >> 16));
        wv[2 * e] = b2f((uint16_t)wu[e]); wv[2 * e + 1] = b2f((uint16_t)(wu[e] >> 16));
      }
#pragma unroll
      for (int j = 0; j < 3; ++j) {
        f32x4 wa = *(const f32x4*)(wtd + j * 128 + cq * 8);
        f32x4 wb = *(const f32x4*)(wtd + j * 128 + cq * 8 + 4);
        f32x4 va = *(const f32x4*)(wtw + j * 128 + cq * 8);
        f32x4 vb = *(const f32x4*)(wtw + j * 128 + cq * 8 + 4);
#pragma unroll
        for (int e = 0; e < 4; ++e) {
          accd[j] += dv[e] * wa[e] + dv[e + 4] * wb[e];
          accw[j] += wv[e] * va[e] + wv[e + 4] * vb[e];
        }
      }
    }
  }
  size_t ob = ((size_t)n * PXI + px) * 3;
#pragma unroll
  for (int j = 0; j < 3; ++j) {
    out_delta[ob + j] = accd[j];
    out_weight[ob + j] = sigm(accw[j]);
  }
}

extern "C" void kernel_launch(void* const* d_in, const int* in_sizes, int n_in,
                              void* d_out, int out_size, void* d_ws, size_t ws_size,
                              hipStream_t stream) {
  (void)in_sizes; (void)n_in; (void)out_size; (void)ws_size;
  const float* net  = (const float*)d_in[0];
  const float* inp  = (const float*)d_in[1];
  const float* corr = (const float*)d_in[2];
  const float* flow = (const float*)d_in[3];
  const float* w_ce1 = (const float*)d_in[4];   const float* b_ce1 = (const float*)d_in[5];
  const float* w_ce2 = (const float*)d_in[6];   const float* b_ce2 = (const float*)d_in[7];
  const float* w_fe1 = (const float*)d_in[8];   const float* b_fe1 = (const float*)d_in[9];
  const float* w_fe2 = (const float*)d_in[10];  const float* b_fe2 = (const float*)d_in[11];
  const float* w_z  = (const float*)d_in[12];   const float* b_z  = (const float*)d_in[13];
  const float* w_r  = (const float*)d_in[14];   const float* b_r  = (const float*)d_in[15];
  const float* w_q  = (const float*)d_in[16];   const float* b_q  = (const float*)d_in[17];
  const float* w_d1 = (const float*)d_in[18];   const float* b_d1 = (const float*)d_in[19];
  const float* w_d2 = (const float*)d_in[20];   const float* b_d2 = (const float*)d_in[21];
  const float* w_w1 = (const float*)d_in[22];   const float* b_w1 = (const float*)d_in[23];
  const float* w_w2 = (const float*)d_in[24];   const float* b_w2 = (const float*)d_in[25];

  uint8_t* ws = (uint8_t*)d_ws;
  size_t off = 0;
  auto alloc = [&](size_t b) { size_t o = off; off += (b + 255) & ~(size_t)255; return o; };
  uint16_t* wpk_ce1 = (uint16_t*)(ws + alloc(57344));
  uint16_t* wpk_ce2 = (uint16_t*)(ws + alloc(294912));
  uint16_t* wpk_fe1 = (uint16_t*)(ws + alloc(40960));
  uint16_t* wpk_fe2 = (uint16_t*)(ws + alloc(147456));
  uint16_t* wpk_zr  = (uint16_t*)(ws + alloc(2064384));
  uint16_t* wpk_q   = (uint16_t*)(ws + alloc(1032192));
  uint16_t* wpk_dw  = (uint16_t*)(ws + alloc(589824));
  uint16_t* X448 = (uint16_t*)(ws + alloc((size_t)BNI * PXI * 448 * 2)); // [h|inp|c|fl]
  uint16_t* C1   = (uint16_t*)(ws + alloc((size_t)BNI * PXI * 128 * 2)); // ce1 out -> HN
  uint16_t* F1   = (uint16_t*)(ws + alloc((size_t)BNI * PXI * 128 * 2)); // fe1 out
  uint16_t* Zb   = (uint16_t*)(ws + alloc((size_t)BNI * PXI * 128 * 2)); // z -> D1
  uint16_t* RHb  = (uint16_t*)(ws + alloc((size_t)BNI * PXI * 128 * 2)); // r*h -> W1
  // F2col (24*4800*160 bf16 = 36.9MB) aliases Zb+head(RHb): dead before zr writes.
  uint16_t* F2col = Zb;

  auto packs = [&](const float* w, uint16_t* dst, int Cout, int Cin, int taps,
                   int CPAD, int cobase, int cogT) {
    int total = Cout * CPAD * taps;
    pack_w<<<(total + 255) / 256, 256, 0, stream>>>(w, dst, Cout, Cin, taps, CPAD, cobase, cogT);
  };
  packs(w_ce1, wpk_ce1, 128, 197, 1, 224, 0, 8);
  packs(w_ce2, wpk_ce2, 128, 128, 9, 128, 0, 8);
  packs(w_fe1, wpk_fe1, 128, 147, 1, 160, 0, 8);
  packs(w_fe2, wpk_fe2, 64, 128, 9, 128, 0, 4);
  packs(w_z,  wpk_zr, 128, 448, 9, 448, 0, 16);
  packs(w_r,  wpk_zr, 128, 448, 9, 448, 128, 16);
  packs(w_q,  wpk_q,  128, 448, 9, 448, 0, 8);
  packs(w_d1, wpk_dw, 128, 128, 9, 128, 0, 16);
  packs(w_w1, wpk_dw, 128, 128, 9, 128, 128, 16);

  nchw2nhwc<<<dim3(19, BNI), 256, 0, stream>>>(net, X448, 128, 448, 0);
  nchw2nhwc<<<dim3(19, BNI), 256, 0, stream>>>(inp, X448, 128, 448, 128);
  im2col_fe1<<<dim3(60, BNI), 256, 0, stream>>>(flow, F2col);

  const int GR = BNI * 30;  // 720 rowgroups (2 rows each), divisible by 8
  ConvParams p;
  // ---- fe1 as 1x1 MFMA conv: F2col(160) -> F1, relu
  memset(&p, 0, sizeof(p));
  for (int ks = 0; ks < 5; ++ks) p.srcs[ks] = SrcDesc{F2col, PXI * 160, ks * 32, 160, 0, 0};
  p.KS = 5; p.cog_total = 8; p.ncb = 1; p.mode = 0;
  p.wpk = wpk_fe1; p.bias0 = b_fe1;
  p.out0 = F1; p.ostride0 = 128; p.ochoff0 = 0;
  conv_mfma<1, 2><<<GR, 256, 0, stream>>>(p);
  // ---- ce1: 1x1, corr(197 f32) -> C1, relu
  memset(&p, 0, sizeof(p));
  for (int ks = 0; ks < 7; ++ks) p.srcs[ks] = SrcDesc{corr, 197 * PXI, ks * 32, 0, 197, 1};
  p.KS = 7; p.cog_total = 8; p.ncb = 1; p.mode = 0;
  p.wpk = wpk_ce1; p.bias0 = b_ce1;
  p.out0 = C1; p.ostride0 = 128; p.ochoff0 = 0;
  conv_mfma<1, 2><<<GR, 256, 0, stream>>>(p);
  // ---- ce2: 3x3, C1 -> X448[256:384), relu
  memset(&p, 0, sizeof(p));
  for (int ks = 0; ks < 4; ++ks) p.srcs[ks] = SrcDesc{C1, PXI * 128, ks * 32, 128, 0, 0};
  p.KS = 4; p.cog_total = 8; p.ncb = 1; p.mode = 0;
  p.wpk = wpk_ce2; p.bias0 = b_ce2;
  p.out0 = X448; p.ostride0 = 448; p.ochoff0 = 256;
  conv_mfma<3, 2><<<GR, 256, 0, stream>>>(p);
  // ---- fe2: 3x3, F1 -> X448[384:448), relu (Cout=64 -> CW=1)
  memset(&p, 0, sizeof(p));
  for (int ks = 0; ks < 4; ++ks) p.srcs[ks] = SrcDesc{F1, PXI * 128, ks * 32, 128, 0, 0};
  p.KS = 4; p.cog_total = 4; p.ncb = 1; p.mode = 0;
  p.wpk = wpk_fe2; p.bias0 = b_fe2;
  p.out0 = X448; p.ostride0 = 448; p.ochoff0 = 384;
  conv_mfma<3, 1><<<GR, 256, 0, stream>>>(p);
  // ---- z & r fused: 3x3, X448 -> Z(Zb), RH(RHb)
  memset(&p, 0, sizeof(p));
  for (int ks = 0; ks < 14; ++ks) p.srcs[ks] = SrcDesc{X448, PXI * 448, ks * 32, 448, 0, 0};
  p.KS = 14; p.cog_total = 16; p.ncb = 2; p.mode = 1;
  p.wpk = wpk_zr; p.bias0 = b_z; p.bias1 = b_r;
  p.out0 = Zb; p.out1 = RHb; p.hbf = X448;
  conv_mfma<3, 2><<<GR * 2, 256, 0, stream>>>(p);
  // ---- q: 3x3, [RH | X448[128:448)] -> tanh, GRU update -> d_out(net) + HN(C1)
  memset(&p, 0, sizeof(p));
  for (int ks = 0; ks < 4; ++ks)  p.srcs[ks] = SrcDesc{RHb, PXI * 128, ks * 32, 128, 0, 0};
  for (int ks = 4; ks < 14; ++ks) p.srcs[ks] = SrcDesc{X448, PXI * 448, 128 + (ks - 4) * 32, 448, 0, 0};
  p.KS = 14; p.cog_total = 8; p.ncb = 1; p.mode = 2;
  p.wpk = wpk_q; p.bias0 = b_q;
  p.out0 = C1; p.zbuf = Zb; p.netf32 = net; p.houtf32 = (float*)d_out;
  conv_mfma<3, 2><<<GR, 256, 0, stream>>>(p);
  // ---- d1 & w1 fused: 3x3, HN(C1) -> D1(Zb), W1(RHb), relu
  memset(&p, 0, sizeof(p));
  for (int ks = 0; ks < 4; ++ks) p.srcs[ks] = SrcDesc{C1, PXI * 128, ks * 32, 128, 0, 0};
  p.KS = 4; p.cog_total = 16; p.ncb = 2; p.mode = 0;
  p.wpk = wpk_dw; p.bias0 = b_d1; p.bias1 = b_w1;
  p.out0 = Zb; p.ostride0 = 128; p.ochoff0 = 0;
  p.out1 = RHb; p.ostride1 = 128; p.ochoff1 = 0;
  conv_mfma<3, 2><<<GR * 2, 256, 0, stream>>>(p);
  // ---- heads final convs
  float* dout = (float*)d_out;
  dw2_kernel<<<450, 256, 0, stream>>>(Zb, RHb, w_d2, w_w2, b_d2, b_w2,
                                      dout + 14745600, dout + 15091200);
}

// Round 16
// 915.359 us; speedup vs baseline: 1.2582x; 1.0141x over previous
//
#include <hip/hip_runtime.h>
#include <stdint.h>
#include <string.h>

#define PXI 4800
#define BNI 24

typedef short bf16x8 __attribute__((ext_vector_type(8)));
typedef float f32x4 __attribute__((ext_vector_type(4)));

__device__ __forceinline__ uint16_t f2b(float f) {
  uint32_t u = __float_as_uint(f);
  u += 0x7fffu + ((u >> 16) & 1u);
  return (uint16_t)(u >> 16);
}
__device__ __forceinline__ float b2f(uint16_t b) {
  return __uint_as_float(((uint32_t)b) << 16);
}
__device__ __forceinline__ float sigm(float x) {
  return 1.0f / (1.0f + __expf(-x));
}

struct SrcDesc {
  const void* p;
  int nstride;    // elements per image
  int coff;       // starting channel of this 32-ch kstep within source
  int pixstride;  // NHWC channel count (bf16 path)
  int creal;      // valid channel bound (f32 path)
  int is_f32;     // 1 = NCHW f32 source, 0 = NHWC bf16 source
};

struct ConvParams {
  SrcDesc srcs[14];
  int KS, cog_total, ncb, mode;
  const uint16_t* wpk;
  const float* bias0;
  const float* bias1;
  uint16_t* out0; int ostride0, ochoff0;
  uint16_t* out1; int ostride1, ochoff1;
  const uint16_t* zbuf;   // mode 2
  const uint16_t* hbf;    // mode 1: h as bf16 NHWC stride 448
  const float* netf32;    // mode 2: h (f32 NCHW)
  float* houtf32;         // mode 2: net_out region of d_out
};

// Implicit-GEMM conv v4.4: v4.1 (verified 927us / zr 245us / VGPR 84) plus
// ONE register-neutral change: TWO ks-steps per barrier pair. Stage
// srcs[ks]->buf0 and srcs[ks+1]->buf1 back-to-back (2x staging MLP), one
// barrier, then both tap-blocks sequentially. No loop-spanning register
// state: staging passes and tap-blocks reuse the same temps (lambda inlined
// twice); only additions are a flag + one pointer. LDS 21->42KB (3 blocks/CU
// still fits: 126<=160KB). Barrier pairs per conv halved.
template<int DSPAN, int CW>
__global__ __launch_bounds__(256, 2) void conv_mfma(ConvParams P) {
  constexpr int PAD = (DSPAN - 1) / 2;
  constexpr int NR = 2;
  constexpr int NRS = NR + DSPAN - 1;
  constexpr int UP = 80 + 2 * PAD;
  constexpr int UPITCH = 82 * 64;
  constexpr int NT = DSPAN * DSPAN;
  constexpr int CB = 4 * CW;
  __shared__ __align__(16) uint8_t smem[2][NRS * UPITCH];
  const int tid = threadIdx.x;
  const int wave = tid >> 6, lane = tid & 63;
  const int bx = blockIdx.x;
  const int total = gridDim.x;
  const int id = (bx & 7) * (total >> 3) + (bx >> 3);  // XCD-contiguous
  const int cbk = id % P.ncb;
  const int rg = id / P.ncb;           // cog-blocks of same rows adjacent
  const int n = rg / 30, y0 = (rg - n * 30) * NR;
  const int cog0 = cbk * CB + wave * CW;

  f32x4 acc[CW][NR][5];
#pragma unroll
  for (int c = 0; c < CW; ++c)
#pragma unroll
    for (int r = 0; r < NR; ++r)
#pragma unroll
      for (int t = 0; t < 5; ++t)
        acc[c][r][t] = f32x4{0.f, 0.f, 0.f, 0.f};

  const int pxl = lane & 15;
  const int hi16 = (lane >> 4) * 16;
  const int tapstride = P.cog_total * P.KS * 512;   // elements per tap
  const uint16_t* wl = P.wpk + lane * 8;

  // block-cooperative B staging into buffer sb (v4.1 body verbatim)
  auto stageB = [&](int ksi, uint8_t* sb) {
    const SrcDesc d = P.srcs[ksi];
    if (!d.is_f32) {
      const uint16_t* bp = (const uint16_t*)d.p + (size_t)n * d.nstride + d.coff;
      for (int c = tid; c < NRS * UP * 4; c += 256) {
        int rs = c / (UP * 4);
        int rem = c - rs * (UP * 4);
        int u = rem >> 2, kq = rem & 3;
        int ysrc = y0 + rs - PAD;
        int xs = u - PAD;
        uint4 v; v.x = 0; v.y = 0; v.z = 0; v.w = 0;
        if ((unsigned)ysrc < 60u && (unsigned)xs < 80u)
          v = *(const uint4*)(bp + (size_t)(ysrc * 80 + xs) * d.pixstride + kq * 8);
        *(uint4*)(sb + rs * UPITCH + ((u * 64 + kq * 16) ^ ((u & 7) << 4))) = v;
      }
    } else {
      // f32 NCHW path (ce1 only: 1x1, pad 0)
      const int ci = tid >> 3, xg = tid & 7;
      const bool cok = (d.coff + ci) < d.creal;
      const float* fp = (const float*)d.p + (size_t)n * d.nstride +
                        (size_t)(d.coff + ci) * PXI;
#pragma unroll
      for (int rs = 0; rs < NRS; ++rs) {
#pragma unroll
        for (int j = 0; j < 10; ++j) {
          int x = xg + j * 8;
          float v = cok ? fp[(y0 + rs) * 80 + x] : 0.f;
          *(uint16_t*)(sb + rs * UPITCH + ((x * 64 + ci * 2) ^ ((x & 7) << 4))) = f2b(v);
        }
      }
    }
  };

  // tap loop on buffer sb with preloaded tap-0 A frags (v4.1 body verbatim)
  auto tapblock = [&](const uint16_t* wk0, const uint8_t* sb, bf16x8* acur) {
#pragma unroll 1
    for (int tap = 0; tap < NT; ++tap) {
      bf16x8 anx[CW];
      if (tap + 1 < NT) {
        const uint16_t* wn = wk0 + (size_t)(tap + 1) * tapstride;
#pragma unroll
        for (int c = 0; c < CW; ++c)
          anx[c] = *(const bf16x8*)(wn + (size_t)c * (P.KS * 512));
      }
      const int dy = (DSPAN == 3) ? ((tap * 11) >> 5) : 0;
      const int dx = tap - dy * 3;
      const int u0 = pxl + dx;
      const uint8_t* brow = sb + dy * UPITCH + ((u0 * 64 + hi16) ^ ((u0 & 7) << 4));
#pragma unroll
      for (int r = 0; r < NR; ++r) {
#pragma unroll
        for (int t = 0; t < 5; ++t) {
          bf16x8 b = *(const bf16x8*)(brow + r * UPITCH + t * 1024);
#pragma unroll
          for (int c = 0; c < CW; ++c)
            acc[c][r][t] = __builtin_amdgcn_mfma_f32_16x16x32_bf16(acur[c], b, acc[c][r][t], 0, 0, 0);
        }
      }
      if (tap + 1 < NT) {
#pragma unroll
        for (int c = 0; c < CW; ++c)
          acur[c] = anx[c];
      }
    }
  };

  for (int ks = 0; ks < P.KS; ks += 2) {
    __syncthreads();   // prev-pair tap reads (both buffers) done
    // ---- A tap-0 prefetch for ks: overlaps both staging passes
    const uint16_t* wk0 = wl + ((size_t)cog0 * P.KS + ks) * 512;
    bf16x8 acur[CW];
#pragma unroll
    for (int c = 0; c < CW; ++c)
      acur[c] = *(const bf16x8*)(wk0 + (size_t)c * (P.KS * 512));
    // ---- stage both ks into separate buffers (double staging MLP)
    const bool two = (ks + 1 < P.KS);
    stageB(ks, smem[0]);
    if (two) stageB(ks + 1, smem[1]);
    __syncthreads();
    // ---- tap blocks
    tapblock(wk0, smem[0], acur);
    if (two) {
      const uint16_t* wk1 = wk0 + 512;   // ks+1 stride within wpk
#pragma unroll
      for (int c = 0; c < CW; ++c)
        acur[c] = *(const bf16x8*)(wk1 + (size_t)c * (P.KS * 512));
      tapblock(wk1, smem[1], acur);
    }
  }

  // ---- epilogue
  const int rq = lane >> 4;
  for (int c = 0; c < CW; ++c) {
    const int co0 = (cog0 + c) * 16 + rq * 4;
    for (int r = 0; r < NR; ++r) {
      for (int t = 0; t < 5; ++t) {
        const int px = (y0 + r) * 80 + t * 16 + pxl;
        const size_t gpix = (size_t)n * PXI + px;
        float v[4];
#pragma unroll
        for (int rr = 0; rr < 4; ++rr) {
          int co = co0 + rr;
          float bia = (P.bias1 && co >= 128) ? P.bias1[co - 128] : P.bias0[co];
          v[rr] = acc[c][r][t][rr] + bia;
        }
        if (P.mode == 0) {           // relu -> bf16 NHWC (split at co>=128 if out1)
          uint16_t* op; int cb2;
          if (P.out1 && co0 >= 128) { op = P.out1 + gpix * (size_t)P.ostride1 + P.ochoff1; cb2 = co0 - 128; }
          else                      { op = P.out0 + gpix * (size_t)P.ostride0 + P.ochoff0; cb2 = co0; }
          uint64_t w = 0;
#pragma unroll
          for (int rr = 0; rr < 4; ++rr)
            w |= (uint64_t)f2b(fmaxf(v[rr], 0.f)) << (16 * rr);
          *(uint64_t*)(op + cb2) = w;
        } else if (P.mode == 1) {    // z (sigmoid) / r (sigmoid * h_bf16)
          if (co0 < 128) {
            uint64_t w = 0;
#pragma unroll
            for (int rr = 0; rr < 4; ++rr)
              w |= (uint64_t)f2b(sigm(v[rr])) << (16 * rr);
            *(uint64_t*)(P.out0 + gpix * 128 + co0) = w;
          } else {
            uint64_t hw = *(const uint64_t*)(P.hbf + gpix * 448 + (co0 - 128));
            uint64_t w = 0;
#pragma unroll
            for (int rr = 0; rr < 4; ++rr) {
              float rgt = sigm(v[rr]);
              float h = b2f((uint16_t)(hw >> (16 * rr)));
              w |= (uint64_t)f2b(rgt * h) << (16 * rr);
            }
            *(uint64_t*)(P.out1 + gpix * 128 + (co0 - 128)) = w;
          }
        } else {                     // mode 2: q=tanh, GRU update, dual write
          uint64_t zw = *(const uint64_t*)(P.zbuf + gpix * 128 + co0);
          uint64_t w = 0;
#pragma unroll
          for (int rr = 0; rr < 4; ++rr) {
            float qv = tanhf(v[rr]);
            float z = b2f((uint16_t)(zw >> (16 * rr)));
            size_t hidx = ((size_t)n * 128 + co0 + rr) * PXI + px;
            float h = P.netf32[hidx];
            float hn = (1.f - z) * h + z * qv;
            P.houtf32[hidx] = hn;
            w |= (uint64_t)f2b(hn) << (16 * rr);
          }
          *(uint64_t*)(P.out0 + gpix * 128 + co0) = w;
        }
      }
    }
  }
}

// f32 NCHW -> bf16 NHWC transpose
__global__ __launch_bounds__(256) void nchw2nhwc(const float* src, uint16_t* dst,
                                                 int C, int pixstride, int choff) {
  const int n = blockIdx.y;
  const int px = blockIdx.x * 256 + threadIdx.x;
  if (px >= PXI) return;
  const float* sp = src + (size_t)n * C * PXI + px;
  uint16_t* dp = dst + ((size_t)n * PXI + px) * pixstride + choff;
  for (int c = 0; c < C; c += 8) {
    uint32_t pk[4];
#pragma unroll
    for (int j = 0; j < 4; ++j) {
      uint32_t lo = f2b(sp[(size_t)(c + 2 * j) * PXI]);
      uint32_t hi = f2b(sp[(size_t)(c + 2 * j + 1) * PXI]);
      pk[j] = lo | (hi << 16);
    }
    uint4 v; v.x = pk[0]; v.y = pk[1]; v.z = pk[2]; v.w = pk[3];
    *(uint4*)(dp + c) = v;
  }
}

// im2col for fe1: flow (24x3x60x80 f32) -> F2col[n][px][160] bf16,
// k = ci*49 + ky*7 + kx (147 real, pad->160), pad=3 halo, OOB=0.
__global__ __launch_bounds__(256) void im2col_fe1(const float* flow, uint16_t* F2col) {
  __shared__ float tile[3 * 7 * 88];
  __shared__ uint32_t lut[160];
  const int y = blockIdx.x, n = blockIdx.y;
  const int tid = threadIdx.x;
  if (tid < 160) {
    int k = tid;
    if (k < 147) {
      int ci = k / 49, rem = k - ci * 49;
      int ky = rem / 7, kx = rem - ky * 7;
      lut[k] = (uint32_t)ci | ((uint32_t)ky << 8) | ((uint32_t)kx << 16);
    } else lut[k] = 0xFFFFFFFFu;
  }
  for (int c = tid; c < 3 * 7 * 86; c += 256) {
    int ci = c / 602, rem = c - ci * 602;
    int ky = rem / 86, xi = rem - ky * 86;
    int ysrc = y + ky - 3, x = xi - 3;
    float v = 0.f;
    if ((unsigned)ysrc < 60u && (unsigned)x < 80u)
      v = flow[((size_t)(n * 3 + ci) * 60 + ysrc) * 80 + x];
    tile[(ci * 7 + ky) * 88 + xi] = v;
  }
  __syncthreads();
  uint16_t* op = F2col + ((size_t)n * PXI + y * 80) * 160;
  for (int c = tid; c < 80 * 20; c += 256) {
    int px = c / 20, q = c - px * 20;
    int k0 = q * 8;
    uint32_t pk[4];
#pragma unroll
    for (int j = 0; j < 4; ++j) {
      uint16_t w0 = 0, w1 = 0;
      uint32_t l0 = lut[k0 + 2 * j], l1 = lut[k0 + 2 * j + 1];
      if (l0 != 0xFFFFFFFFu)
        w0 = f2b(tile[((l0 & 0xFF) * 7 + ((l0 >> 8) & 0xFF)) * 88 + px + (l0 >> 16)]);
      if (l1 != 0xFFFFFFFFu)
        w1 = f2b(tile[((l1 & 0xFF) * 7 + ((l1 >> 8) & 0xFF)) * 88 + px + (l1 >> 16)]);
      pk[j] = (uint32_t)w0 | ((uint32_t)w1 << 16);
    }
    uint4 v; v.x = pk[0]; v.y = pk[1]; v.z = pk[2]; v.w = pk[3];
    *(uint4*)(op + (size_t)px * 160 + k0) = v;
  }
}

// Pack f32 OIHW weights -> bf16 MFMA-fragment-order:
// wpk[((tap*cogTotal + cog)*KS + ks)*512 + lane*8 + e],
// lane = (co&15) | (((ci>>3)&3)<<4), e = ci&7, ks = ci>>5. Cin zero-padded to CPAD.
__global__ __launch_bounds__(256) void pack_w(const float* w, uint16_t* wpk,
    int Cout, int Cin, int taps, int CPAD, int cobase, int cogTotal) {
  int idx = blockIdx.x * 256 + threadIdx.x;
  int total = Cout * CPAD * taps;
  if (idx >= total) return;
  int ci = idx % CPAD;
  int rest = idx / CPAD;
  int co = rest % Cout;
  int tap = rest / Cout;
  float v = (ci < Cin) ? w[((size_t)co * Cin + ci) * taps + tap] : 0.f;
  int cog = (cobase + co) >> 4;
  int ks = ci >> 5;
  int lane = ((cobase + co) & 15) | (((ci >> 3) & 3) << 4);
  int KS = CPAD >> 5;
  size_t off = ((size_t)(tap * cogTotal + cog) * KS + ks) * 512 + lane * 8 + (ci & 7);
  wpk[off] = f2b(v);
}

// heads conv2: 3x3, 128->3 each (delta raw, weight sigmoid), vectorized loads.
// wl layout: [src][tap][j][ci] for float4 LDS reads.
__global__ __launch_bounds__(256) void dw2_kernel(const uint16_t* D1, const uint16_t* W1,
    const float* wd, const float* wwt, const float* bd, const float* bw,
    float* out_delta, float* out_weight) {
  __shared__ float wl[2 * 9 * 3 * 128];
  const int tid = threadIdx.x;
  for (int c = tid; c < 6912; c += 256) {
    int s = c / 3456, rem = c - s * 3456;
    int j = rem / 1152, rem2 = rem - j * 1152;
    int ci = rem2 / 9, tap = rem2 - ci * 9;
    const float* src = s ? wwt : wd;
    wl[((s * 9 + tap) * 3 + j) * 128 + ci] = src[rem];
  }
  __syncthreads();
  int gid = blockIdx.x * 256 + tid;
  if (gid >= BNI * PXI) return;
  int n = gid / PXI, px = gid - n * PXI;
  int y = px / 80, x = px - y * 80;
  float accd[3] = {bd[0], bd[1], bd[2]};
  float accw[3] = {bw[0], bw[1], bw[2]};
  for (int tap = 0; tap < 9; ++tap) {
    int dy = tap / 3, dxm = tap - dy * 3;
    int ys = y + dy - 1, xs = x + dxm - 1;
    if ((unsigned)ys >= 60u || (unsigned)xs >= 80u) continue;
    const uint16_t* dp = D1 + ((size_t)n * PXI + ys * 80 + xs) * 128;
    const uint16_t* wp = W1 + ((size_t)n * PXI + ys * 80 + xs) * 128;
    const float* wtd = &wl[(0 * 9 + tap) * 3 * 128];
    const float* wtw = &wl[(9 + tap) * 3 * 128];
    for (int cq = 0; cq < 16; ++cq) {
      uint4 dv4 = *(const uint4*)(dp + cq * 8);
      uint4 wv4 = *(const uint4*)(wp + cq * 8);
      float dv[8], wv[8];
      const uint32_t* du = (const uint32_t*)&dv4;
      const uint32_t* wu = (const uint32_t*)&wv4;
#pragma unroll
      for (int e = 0; e < 4; ++e) {
        dv[2 * e] = b2f((uint16_t)du[e]); dv[2 * e + 1] = b2f((uint16_t)(du[e] >> 16));
        wv[2 * e] = b2f((uint16_t)wu[e]); wv[2 * e + 1] = b2f((uint16_t)(wu[e] >> 16));
      }
#pragma unroll
      for (int j = 0; j < 3; ++j) {
        f32x4 wa = *(const f32x4*)(wtd + j * 128 + cq * 8);
        f32x4 wb = *(const f32x4*)(wtd + j * 128 + cq * 8 + 4);
        f32x4 va = *(const f32x4*)(wtw + j * 128 + cq * 8);
        f32x4 vb = *(const f32x4*)(wtw + j * 128 + cq * 8 + 4);
#pragma unroll
        for (int e = 0; e < 4; ++e) {
          accd[j] += dv[e] * wa[e] + dv[e + 4] * wb[e];
          accw[j] += wv[e] * va[e] + wv[e + 4] * vb[e];
        }
      }
    }
  }
  size_t ob = ((size_t)n * PXI + px) * 3;
#pragma unroll
  for (int j = 0; j < 3; ++j) {
    out_delta[ob + j] = accd[j];
    out_weight[ob + j] = sigm(accw[j]);
  }
}

extern "C" void kernel_launch(void* const* d_in, const int* in_sizes, int n_in,
                              void* d_out, int out_size, void* d_ws, size_t ws_size,
                              hipStream_t stream) {
  (void)in_sizes; (void)n_in; (void)out_size; (void)ws_size;
  const float* net  = (const float*)d_in[0];
  const float* inp  = (const float*)d_in[1];
  const float* corr = (const float*)d_in[2];
  const float* flow = (const float*)d_in[3];
  const float* w_ce1 = (const float*)d_in[4];   const float* b_ce1 = (const float*)d_in[5];
  const float* w_ce2 = (const float*)d_in[6];   const float* b_ce2 = (const float*)d_in[7];
  const float* w_fe1 = (const float*)d_in[8];   const float* b_fe1 = (const float*)d_in[9];
  const float* w_fe2 = (const float*)d_in[10];  const float* b_fe2 = (const float*)d_in[11];
  const float* w_z  = (const float*)d_in[12];   const float* b_z  = (const float*)d_in[13];
  const float* w_r  = (const float*)d_in[14];   const float* b_r  = (const float*)d_in[15];
  const float* w_q  = (const float*)d_in[16];   const float* b_q  = (const float*)d_in[17];
  const float* w_d1 = (const float*)d_in[18];   const float* b_d1 = (const float*)d_in[19];
  const float* w_d2 = (const float*)d_in[20];   const float* b_d2 = (const float*)d_in[21];
  const float* w_w1 = (const float*)d_in[22];   const float* b_w1 = (const float*)d_in[23];
  const float* w_w2 = (const float*)d_in[24];   const float* b_w2 = (const float*)d_in[25];

  uint8_t* ws = (uint8_t*)d_ws;
  size_t off = 0;
  auto alloc = [&](size_t b) { size_t o = off; off += (b + 255) & ~(size_t)255; return o; };
  uint16_t* wpk_ce1 = (uint16_t*)(ws + alloc(57344));
  uint16_t* wpk_ce2 = (uint16_t*)(ws + alloc(294912));
  uint16_t* wpk_fe1 = (uint16_t*)(ws + alloc(40960));
  uint16_t* wpk_fe2 = (uint16_t*)(ws + alloc(147456));
  uint16_t* wpk_zr  = (uint16_t*)(ws + alloc(2064384));
  uint16_t* wpk_q   = (uint16_t*)(ws + alloc(1032192));
  uint16_t* wpk_dw  = (uint16_t*)(ws + alloc(589824));
  uint16_t* X448 = (uint16_t*)(ws + alloc((size_t)BNI * PXI * 448 * 2)); // [h|inp|c|fl]
  uint16_t* C1   = (uint16_t*)(ws + alloc((size_t)BNI * PXI * 128 * 2)); // ce1 out -> HN
  uint16_t* F1   = (uint16_t*)(ws + alloc((size_t)BNI * PXI * 128 * 2)); // fe1 out
  uint16_t* Zb   = (uint16_t*)(ws + alloc((size_t)BNI * PXI * 128 * 2)); // z -> D1
  uint16_t* RHb  = (uint16_t*)(ws + alloc((size_t)BNI * PXI * 128 * 2)); // r*h -> W1
  // F2col (24*4800*160 bf16 = 36.9MB) aliases Zb+head(RHb): dead before zr writes.
  uint16_t* F2col = Zb;

  auto packs = [&](const float* w, uint16_t* dst, int Cout, int Cin, int taps,
                   int CPAD, int cobase, int cogT) {
    int total = Cout * CPAD * taps;
    pack_w<<<(total + 255) / 256, 256, 0, stream>>>(w, dst, Cout, Cin, taps, CPAD, cobase, cogT);
  };
  packs(w_ce1, wpk_ce1, 128, 197, 1, 224, 0, 8);
  packs(w_ce2, wpk_ce2, 128, 128, 9, 128, 0, 8);
  packs(w_fe1, wpk_fe1, 128, 147, 1, 160, 0, 8);
  packs(w_fe2, wpk_fe2, 64, 128, 9, 128, 0, 4);
  packs(w_z,  wpk_zr, 128, 448, 9, 448, 0, 16);
  packs(w_r,  wpk_zr, 128, 448, 9, 448, 128, 16);
  packs(w_q,  wpk_q,  128, 448, 9, 448, 0, 8);
  packs(w_d1, wpk_dw, 128, 128, 9, 128, 0, 16);
  packs(w_w1, wpk_dw, 128, 128, 9, 128, 128, 16);

  nchw2nhwc<<<dim3(19, BNI), 256, 0, stream>>>(net, X448, 128, 448, 0);
  nchw2nhwc<<<dim3(19, BNI), 256, 0, stream>>>(inp, X448, 128, 448, 128);
  im2col_fe1<<<dim3(60, BNI), 256, 0, stream>>>(flow, F2col);

  const int GR = BNI * 30;  // 720 rowgroups (2 rows each), divisible by 8
  ConvParams p;
  // ---- fe1 as 1x1 MFMA conv: F2col(160) -> F1, relu
  memset(&p, 0, sizeof(p));
  for (int ks = 0; ks < 5; ++ks) p.srcs[ks] = SrcDesc{F2col, PXI * 160, ks * 32, 160, 0, 0};
  p.KS = 5; p.cog_total = 8; p.ncb = 1; p.mode = 0;
  p.wpk = wpk_fe1; p.bias0 = b_fe1;
  p.out0 = F1; p.ostride0 = 128; p.ochoff0 = 0;
  conv_mfma<1, 2><<<GR, 256, 0, stream>>>(p);
  // ---- ce1: 1x1, corr(197 f32) -> C1, relu
  memset(&p, 0, sizeof(p));
  for (int ks = 0; ks < 7; ++ks) p.srcs[ks] = SrcDesc{corr, 197 * PXI, ks * 32, 0, 197, 1};
  p.KS = 7; p.cog_total = 8; p.ncb = 1; p.mode = 0;
  p.wpk = wpk_ce1; p.bias0 = b_ce1;
  p.out0 = C1; p.ostride0 = 128; p.ochoff0 = 0;
  conv_mfma<1, 2><<<GR, 256, 0, stream>>>(p);
  // ---- ce2: 3x3, C1 -> X448[256:384), relu
  memset(&p, 0, sizeof(p));
  for (int ks = 0; ks < 4; ++ks) p.srcs[ks] = SrcDesc{C1, PXI * 128, ks * 32, 128, 0, 0};
  p.KS = 4; p.cog_total = 8; p.ncb = 1; p.mode = 0;
  p.wpk = wpk_ce2; p.bias0 = b_ce2;
  p.out0 = X448; p.ostride0 = 448; p.ochoff0 = 256;
  conv_mfma<3, 2><<<GR, 256, 0, stream>>>(p);
  // ---- fe2: 3x3, F1 -> X448[384:448), relu (Cout=64 -> CW=1)
  memset(&p, 0, sizeof(p));
  for (int ks = 0; ks < 4; ++ks) p.srcs[ks] = SrcDesc{F1, PXI * 128, ks * 32, 128, 0, 0};
  p.KS = 4; p.cog_total = 4; p.ncb = 1; p.mode = 0;
  p.wpk = wpk_fe2; p.bias0 = b_fe2;
  p.out0 = X448; p.ostride0 = 448; p.ochoff0 = 384;
  conv_mfma<3, 1><<<GR, 256, 0, stream>>>(p);
  // ---- z & r fused: 3x3, X448 -> Z(Zb), RH(RHb)
  memset(&p, 0, sizeof(p));
  for (int ks = 0; ks < 14; ++ks) p.srcs[ks] = SrcDesc{X448, PXI * 448, ks * 32, 448, 0, 0};
  p.KS = 14; p.cog_total = 16; p.ncb = 2; p.mode = 1;
  p.wpk = wpk_zr; p.bias0 = b_z; p.bias1 = b_r;
  p.out0 = Zb; p.out1 = RHb; p.hbf = X448;
  conv_mfma<3, 2><<<GR * 2, 256, 0, stream>>>(p);
  // ---- q: 3x3, [RH | X448[128:448)] -> tanh, GRU update -> d_out(net) + HN(C1)
  memset(&p, 0, sizeof(p));
  for (int ks = 0; ks < 4; ++ks)  p.srcs[ks] = SrcDesc{RHb, PXI * 128, ks * 32, 128, 0, 0};
  for (int ks = 4; ks < 14; ++ks) p.srcs[ks] = SrcDesc{X448, PXI * 448, 128 + (ks - 4) * 32, 448, 0, 0};
  p.KS = 14; p.cog_total = 8; p.ncb = 1; p.mode = 2;
  p.wpk = wpk_q; p.bias0 = b_q;
  p.out0 = C1; p.zbuf = Zb; p.netf32 = net; p.houtf32 = (float*)d_out;
  conv_mfma<3, 2><<<GR, 256, 0, stream>>>(p);
  // ---- d1 & w1 fused: 3x3, HN(C1) -> D1(Zb), W1(RHb), relu
  memset(&p, 0, sizeof(p));
  for (int ks = 0; ks < 4; ++ks) p.srcs[ks] = SrcDesc{C1, PXI * 128, ks * 32, 128, 0, 0};
  p.KS = 4; p.cog_total = 16; p.ncb = 2; p.mode = 0;
  p.wpk = wpk_dw; p.bias0 = b_d1; p.bias1 = b_w1;
  p.out0 = Zb; p.ostride0 = 128; p.ochoff0 = 0;
  p.out1 = RHb; p.ostride1 = 128; p.ochoff1 = 0;
  conv_mfma<3, 2><<<GR * 2, 256, 0, stream>>>(p);
  // ---- heads final convs
  float* dout = (float*)d_out;
  dw2_kernel<<<450, 256, 0, stream>>>(Zb, RHb, w_d2, w_w2, b_d2, b_w2,
                                      dout + 14745600, dout + 15091200);
}